// Round 1
// baseline (377.377 us; speedup 1.0000x reference)
//
#include <hip/hip_runtime.h>
#include <hip/hip_bf16.h>

// LearnableTensorSquare: out[z,k] = sum_ij (W@T)[k,i*128+j] * f[z,i] * f[z,j]
// f = [ones, features], Z=16384, N=128, K=128, DIM_TS=2080.
// Stage 1 (k_wt): K3 = W@T as bf16 into d_ws (HBM-bound on T stream, ~21us floor).
// Stage 2 (k_qf): per 64-z block, loop i: A_i[z,j]=f[z,i]*f[z,j] generated into
//   swizzled LDS, B from K3 global (L2-resident), MFMA 16x16x32 bf16.

typedef short bfrag __attribute__((ext_vector_type(8)));  // 8 x bf16 (4 VGPR)
typedef float f32x4 __attribute__((ext_vector_type(4)));

#define NIN  127
#define KOUT 128
#define DTS  2080
#define PTOT 16384   // N*N

static __device__ __forceinline__ ushort f2bf(float x) {
  __hip_bfloat16 h = __float2bfloat16(x);
  return __builtin_bit_cast(ushort, h);
}
static __device__ __forceinline__ float bf2f(ushort u) {
  union { unsigned int u; float f; } t;
  t.u = ((unsigned int)u) << 16;
  return t.f;
}

// ---------------- Stage 1: K3[k][p] = sum_d W[k][d] * T[d][p], bf16 out ----------------
// grid 256 (p-tiles of 64), block 256 = 4 waves; wave w covers k-rows [w*32, w*32+32).
__global__ __launch_bounds__(256) void k_wt(const float* __restrict__ W,
                                            const float* __restrict__ T,
                                            ushort* __restrict__ K3) {
  __shared__ ushort Tb[64 * 40];  // [p][d] bf16, padded 32->40 (2-way max conflicts)
  const int t = threadIdx.x;
  const int lane = t & 63;
  const int w = t >> 6;
  const int p0 = blockIdx.x * 64;
  const int c4 = t & 15, dr = t >> 4;
  f32x4 acc[2][4] = {};
  for (int s = 0; s < 65; ++s) {  // 2080 = 65*32
    const int d0 = s * 32;
    __syncthreads();  // prior-step LDS reads done
    // stage T[d0..d0+31][p0..p0+63] -> Tb[p][d] (transposed, f32->bf16)
#pragma unroll
    for (int h = 0; h < 2; ++h) {
      const int d = dr + h * 16;
      const float4 v = *(const float4*)(T + (size_t)(d0 + d) * PTOT + p0 + c4 * 4);
      Tb[(c4 * 4 + 0) * 40 + d] = f2bf(v.x);
      Tb[(c4 * 4 + 1) * 40 + d] = f2bf(v.y);
      Tb[(c4 * 4 + 2) * 40 + d] = f2bf(v.z);
      Tb[(c4 * 4 + 3) * 40 + d] = f2bf(v.w);
    }
    // A-frags straight from global W (f32 -> bf16): row k = l&15 (+m*16), d = (l>>4)*8+e
    bfrag a[2];
#pragma unroll
    for (int m = 0; m < 2; ++m) {
      const float* wp = W + (size_t)(w * 32 + m * 16 + (lane & 15)) * DTS + d0 + ((lane >> 4) << 3);
      const float4 lo = *(const float4*)wp;
      const float4 hi = *(const float4*)(wp + 4);
      a[m][0] = (short)f2bf(lo.x); a[m][1] = (short)f2bf(lo.y);
      a[m][2] = (short)f2bf(lo.z); a[m][3] = (short)f2bf(lo.w);
      a[m][4] = (short)f2bf(hi.x); a[m][5] = (short)f2bf(hi.y);
      a[m][6] = (short)f2bf(hi.z); a[m][7] = (short)f2bf(hi.w);
    }
    __syncthreads();  // Tb ready
#pragma unroll
    for (int nf = 0; nf < 4; ++nf) {
      const bfrag bb = *(const bfrag*)&Tb[(nf * 16 + (lane & 15)) * 40 + ((lane >> 4) << 3)];
      acc[0][nf] = __builtin_amdgcn_mfma_f32_16x16x32_bf16(a[0], bb, acc[0][nf], 0, 0, 0);
      acc[1][nf] = __builtin_amdgcn_mfma_f32_16x16x32_bf16(a[1], bb, acc[1][nf], 0, 0, 0);
    }
  }
  // D layout: col = lane&15 (p), row = (lane>>4)*4 + r (k)
#pragma unroll
  for (int m = 0; m < 2; ++m)
#pragma unroll
    for (int nf = 0; nf < 4; ++nf)
#pragma unroll
      for (int r = 0; r < 4; ++r)
        K3[(size_t)(w * 32 + m * 16 + ((lane >> 4) << 2) + r) * PTOT + p0 + nf * 16 + (lane & 15)] =
            f2bf(acc[m][nf][r]);
}

// ---------------- Stage 2: out[z,k] = sum_i f[z,i] * sum_j f[z,j]*K3[k, i*128+j] -------
// grid 256 (z-tiles of 64), block 256 = 4 waves.
// Wave w: A-gen j-chunk [w*32, w*32+32), MFMA k-cols [w*32, w*32+32).
__global__ __launch_bounds__(256) void k_qf(const float* __restrict__ features,
                                            const ushort* __restrict__ K3,
                                            float* __restrict__ out) {
  __shared__ ushort fT[128 * 68];      // f^T tile: [i][z] bf16, padded 64->68
  __shared__ ushort Ab[2 * 64 * 128];  // 2 i-slices of A_i [z][j] bf16, XOR-swizzled
  const int t = threadIdx.x;
  const int lane = t & 63;
  const int w = t >> 6;
  const int z0 = blockIdx.x * 64;

  // fill fT[i][z]: i=0 -> ones channel
  {
    const int z = t >> 2, jc = t & 3;
#pragma unroll
    for (int e = 0; e < 32; ++e) {
      const int i = jc * 32 + e;
      const float v = (i == 0) ? 1.0f : features[(size_t)(z0 + z) * NIN + (i - 1)];
      fT[i * 68 + z] = f2bf(v);
    }
  }
  __syncthreads();

  // per-thread cache: f[z=lane][j = w*32 + e] in f32
  float fjf[32];
#pragma unroll
  for (int e = 0; e < 32; ++e) fjf[e] = bf2f(fT[(w * 32 + e) * 68 + lane]);

  f32x4 acc[4][2] = {};
  for (int ph = 0; ph < 64; ++ph) {  // 2 i-slices per phase
    const int ibase = ph * 2;
    __syncthreads();  // prior MFMA LDS reads done; Ab writable

    // B-frags from global K3 (L2-resident); issued early, latency hides under A-gen
    bfrag b[2][2][4];
#pragma unroll
    for (int ii = 0; ii < 2; ++ii)
#pragma unroll
      for (int n = 0; n < 2; ++n)
#pragma unroll
        for (int kc = 0; kc < 4; ++kc)
          b[ii][n][kc] = *(const bfrag*)(K3 + ((size_t)(w * 32 + n * 16 + (lane & 15)) << 14) +
                                         (ibase + ii) * 128 + kc * 32 + ((lane >> 4) << 3));

    // A-gen: A_i[z=lane][j] = f[z,i] * f[z,j], bf16, swizzled 16B groups
#pragma unroll
    for (int ii = 0; ii < 2; ++ii) {
      const float fi = bf2f(fT[(ibase + ii) * 68 + lane]);
#pragma unroll
      for (int g = 0; g < 4; ++g) {
        bfrag v;
#pragma unroll
        for (int e = 0; e < 8; ++e) v[e] = (short)f2bf(fi * fjf[g * 8 + e]);
        *(bfrag*)((char*)Ab + ii * 16384 + lane * 256 + ((w * 64 + g * 16) ^ ((lane & 7) << 4))) = v;
      }
    }
    __syncthreads();  // Ab ready (drains b-loads too)

#pragma unroll
    for (int ii = 0; ii < 2; ++ii)
#pragma unroll
      for (int kc = 0; kc < 4; ++kc)
#pragma unroll
        for (int m = 0; m < 4; ++m) {
          const int row = m * 16 + (lane & 15);
          const bfrag a = *(const bfrag*)((const char*)Ab + ii * 16384 + row * 256 +
                                          ((kc * 64 + ((lane >> 4) << 4)) ^ ((row & 7) << 4)));
          acc[m][0] = __builtin_amdgcn_mfma_f32_16x16x32_bf16(a, b[ii][0][kc], acc[m][0], 0, 0, 0);
          acc[m][1] = __builtin_amdgcn_mfma_f32_16x16x32_bf16(a, b[ii][1][kc], acc[m][1], 0, 0, 0);
        }
  }

  // D layout: col = lane&15 (k), row = (lane>>4)*4 + r (z)
#pragma unroll
  for (int m = 0; m < 4; ++m)
#pragma unroll
    for (int n = 0; n < 2; ++n)
#pragma unroll
      for (int r = 0; r < 4; ++r)
        out[(size_t)(z0 + m * 16 + ((lane >> 4) << 2) + r) * KOUT + w * 32 + n * 16 + (lane & 15)] =
            acc[m][n][r];
}

extern "C" void kernel_launch(void* const* d_in, const int* in_sizes, int n_in,
                              void* d_out, int out_size, void* d_ws, size_t ws_size,
                              hipStream_t stream) {
  const float* features = (const float*)d_in[0];  // [16384, 127]
  const float* W        = (const float*)d_in[1];  // [128, 2080]
  const float* T        = (const float*)d_in[2];  // [2080, 16384]
  float* out = (float*)d_out;                     // [16384, 128] f32
  ushort* K3 = (ushort*)d_ws;                     // [128, 16384] bf16 (4 MB)

  k_wt<<<dim3(256), dim3(256), 0, stream>>>(W, T, K3);
  k_qf<<<dim3(256), dim3(256), 0, stream>>>(features, K3, out);
}

// Round 2
// 339.810 us; speedup vs baseline: 1.1106x; 1.1106x over previous
//
#include <hip/hip_runtime.h>

// LearnableTensorSquare: out[z,k] = sum_ij (W@T)[k,i*128+j] * f[z,i] * f[z,j]
// f = [ones, features], Z=16384, N=128, K=128, DIM_TS=2080. All-f16 pipeline.
// k_wf : W -> frag-ready f16 layout (scratch in d_out, pre-memset).
// k_wt : K3 = W@T (f16, into d_ws). Wave-independent, no LDS, no barriers:
//        T B-frags read straight from global (L1-dedup'd), 16 waves/CU.
// k_qf : out = sum_i A_i @ K3_i^T. 32x32x16 f16 MFMA; A gen'd in registers
//        (v_pk_mul_f16); B staged to XOR-swizzled LDS via global_load_lds with
//        pre-swizzled source; i-split x4 + atomicAdd; 2 blocks/CU.

#define ZTOT 16384
#define NIN  127
#define KOUT 128
#define DTS  2080
#define PTOT 16384  // N*N

typedef _Float16 h8 __attribute__((ext_vector_type(8)));
typedef _Float16 h2 __attribute__((ext_vector_type(2)));
typedef float f32x4 __attribute__((ext_vector_type(4)));
typedef float f32x16 __attribute__((ext_vector_type(16)));

static __device__ __forceinline__ void gl16(const void* g, void* l) {
  __builtin_amdgcn_global_load_lds((const __attribute__((address_space(1))) unsigned int*)g,
                                   (__attribute__((address_space(3))) unsigned int*)l, 16, 0, 0);
}

// ---- k_wf: Wf[unit=s*8+kg][lane][e] = f16(W[kg*16+(lane&15)][s*32+(lane>>4)*8+e])
__global__ __launch_bounds__(256) void k_wf(const float* __restrict__ W,
                                            _Float16* __restrict__ Wf) {
  const int t = threadIdx.x, lane = t & 63;
  const int unit = blockIdx.x * 4 + (t >> 6);
  if (unit >= 520) return;
  const int s = unit >> 3, kg = unit & 7;
  const int krow = kg * 16 + (lane & 15);
  const int dbase = s * 32 + ((lane >> 4) << 3);
  h8 v;
#pragma unroll
  for (int e = 0; e < 8; ++e) v[e] = (_Float16)W[(size_t)krow * DTS + dbase + e];
  *(h8*)(Wf + ((size_t)unit * 64 + lane) * 8) = v;
}

// ---- k_wt: K3[k][p] = sum_d W[k][d]*T[d][p], f16 out. grid 1024 (p-tiles of 16).
// Wave w handles k-rows [w*32, w*32+32). No barriers, no LDS.
__global__ __launch_bounds__(256, 4) void k_wt(const float* __restrict__ T,
                                               const _Float16* __restrict__ Wf,
                                               _Float16* __restrict__ K3) {
  const int t = threadIdx.x, lane = t & 63, w = t >> 6;
  const int p0 = blockIdx.x * 16;
  const int prow = p0 + (lane & 15);
  const int dg = (lane >> 4) << 3;
  f32x4 acc0 = {}, acc1 = {};
  const _Float16* wf0 = Wf + ((size_t)(w * 2) * 64 + lane) * 8;
#pragma unroll 2
  for (int s = 0; s < 65; ++s) {
    const size_t tb = (size_t)(s * 32 + dg) * PTOT + prow;
    h8 b;
#pragma unroll
    for (int e = 0; e < 8; ++e) b[e] = (_Float16)T[tb + (size_t)e * PTOT];
    const h8 a0 = *(const h8*)(wf0 + (size_t)s * 4096);
    const h8 a1 = *(const h8*)(wf0 + (size_t)s * 4096 + 512);
    acc0 = __builtin_amdgcn_mfma_f32_16x16x32_f16(a0, b, acc0, 0, 0, 0);
    acc1 = __builtin_amdgcn_mfma_f32_16x16x32_f16(a1, b, acc1, 0, 0, 0);
  }
  const int rbase = (lane >> 4) << 2;
#pragma unroll
  for (int r = 0; r < 4; ++r) {
    K3[(size_t)(w * 32 + rbase + r) * PTOT + prow] = (_Float16)acc0[r];
    K3[(size_t)(w * 32 + 16 + rbase + r) * PTOT + prow] = (_Float16)acc1[r];
  }
}

// ---- k_qf: grid 512 = 128 z-tiles x 4 i-classes; block 256 = 4 waves (2 zg x 2 kg).
// Wave tile 64z x 64k (m=2, n=2, kc=8). B tile [128k][128j] f16 dbuf in LDS.
__global__ __launch_bounds__(256, 2) void k_qf(const float* __restrict__ features,
                                               const _Float16* __restrict__ K3,
                                               float* __restrict__ out) {
  __shared__ __align__(16) _Float16 B0[16384];
  __shared__ __align__(16) _Float16 B1[16384];
  __shared__ _Float16 fT[32 * 136];
  const int t = threadIdx.x, lane = t & 63, w = t >> 6;
  const int zg = w >> 1, kg = w & 1, hg = lane >> 5, l31 = lane & 31;
  const int zb = blockIdx.x >> 2, ic = blockIdx.x & 3;
  const int z0 = zb * 128, i0 = ic * 32;

  // f-tile [z 0..127][j 0..127] f16, XOR-swizzled, into B0 (transient)
  {
    const int row = t >> 1, hf = t & 1;
    const float* fr = features + (size_t)(z0 + row) * NIN;
    const int rs = (row & 7) << 4;
#pragma unroll
    for (int qb = 0; qb < 8; ++qb) {
      h8 v;
#pragma unroll
      for (int e = 0; e < 8; ++e) {
        const int j = hf * 64 + qb * 8 + e;
        v[e] = (j == 0) ? (_Float16)1.0f : (_Float16)fr[j - 1];
      }
      *(h8*)((char*)B0 + row * 256 + (((hf * 8 + qb) * 16) ^ rs)) = v;
    }
  }
  // fT[i 0..31][z 0..127] (fi lookup table, transposed for conflict-free reads)
  {
    const int z = t >> 1, ih = t & 1;
#pragma unroll
    for (int q = 0; q < 16; ++q) {
      const int il = ih * 16 + q, gi = i0 + il;
      const float fv = (gi == 0) ? 1.0f : features[(size_t)(z0 + z) * NIN + gi - 1];
      fT[il * 136 + z] = (_Float16)fv;
    }
  }
  __syncthreads();

  // fj regs: per lane, rows (zg*64 + m*32 + l31), j = kc*16 + hg*8 + e
  h8 fj8[2][8];
#pragma unroll
  for (int m = 0; m < 2; ++m) {
    const int rowm = zg * 64 + m * 32 + l31;
    const int rs = (rowm & 7) << 4;
#pragma unroll
    for (int kc = 0; kc < 8; ++kc)
      fj8[m][kc] = *(const h8*)((const char*)B0 + rowm * 256 + (((kc * 2 + hg) * 16) ^ rs));
  }
  __syncthreads();

  // B staging: linear LDS dest, inverse-swizzled global source (rule #21)
  const _Float16* Kbase = K3 + (size_t)i0 * 128;
#define STAGE_B(BUF, IPH)                                                      \
  {                                                                            \
    const _Float16* src = Kbase + (IPH) * 128;                                 \
    _Pragma("unroll") for (int r = 0; r < 8; ++r) {                            \
      const int Lb = r * 4096 + w * 1024;                                      \
      const int row = (Lb >> 8) + (lane >> 4);                                 \
      const int us = (lane & 15) ^ (row & 7);                                  \
      gl16(src + (size_t)row * PTOT + us * 8, (char*)(BUF) + Lb);              \
    }                                                                          \
  }

  f32x16 acc[2][2] = {};
  STAGE_B(B0, 0)
  __syncthreads();

  const int rs0 = (l31 & 7) << 4;        // swizzle term: rows kg*64(+32)+l31 -> l31&7
  const int brow0 = (kg * 64 + l31) * 256;
  const int brow1 = (kg * 64 + 32 + l31) * 256;

#define PHASE(CURB, NXTB, PH, DO_STAGE)                                        \
  {                                                                            \
    if (DO_STAGE) STAGE_B(NXTB, (PH) + 1)                                      \
    const _Float16 f0 = fT[(PH) * 136 + zg * 64 + l31];                        \
    const _Float16 f1 = fT[(PH) * 136 + zg * 64 + 32 + l31];                   \
    const h2 fi0 = {f0, f0};                                                   \
    const h2 fi1 = {f1, f1};                                                   \
    _Pragma("unroll") for (int kc = 0; kc < 8; ++kc) {                         \
      const int uoff = ((kc * 2 + hg) * 16) ^ rs0;                             \
      const h8 b0 = *(const h8*)((const char*)(CURB) + brow0 + uoff);          \
      const h8 b1 = *(const h8*)((const char*)(CURB) + brow1 + uoff);          \
      h8 a0, a1;                                                               \
      _Pragma("unroll") for (int r = 0; r < 4; ++r) {                          \
        const h2 j0 = {fj8[0][kc][2 * r], fj8[0][kc][2 * r + 1]};              \
        const h2 j1 = {fj8[1][kc][2 * r], fj8[1][kc][2 * r + 1]};              \
        const h2 p0 = fi0 * j0;                                                \
        const h2 p1 = fi1 * j1;                                                \
        a0[2 * r] = p0[0]; a0[2 * r + 1] = p0[1];                              \
        a1[2 * r] = p1[0]; a1[2 * r + 1] = p1[1];                              \
      }                                                                        \
      acc[0][0] = __builtin_amdgcn_mfma_f32_32x32x16_f16(a0, b0, acc[0][0], 0, 0, 0); \
      acc[0][1] = __builtin_amdgcn_mfma_f32_32x32x16_f16(a0, b1, acc[0][1], 0, 0, 0); \
      acc[1][0] = __builtin_amdgcn_mfma_f32_32x32x16_f16(a1, b0, acc[1][0], 0, 0, 0); \
      acc[1][1] = __builtin_amdgcn_mfma_f32_32x32x16_f16(a1, b1, acc[1][1], 0, 0, 0); \
    }                                                                          \
    __syncthreads();                                                           \
  }

  for (int pb = 0; pb < 16; ++pb) {
    PHASE(B0, B1, pb * 2, true)
    PHASE(B1, B0, pb * 2 + 1, (pb < 15))
  }

  // C/D 32x32: col = l31, row = (r&3) + 8*(r>>2) + 4*hg
  const int kq = kg * 64 + l31;
#pragma unroll
  for (int m = 0; m < 2; ++m)
#pragma unroll
    for (int n = 0; n < 2; ++n)
#pragma unroll
      for (int r = 0; r < 16; ++r) {
        const int zr = (r & 3) + ((r >> 2) << 3) + (hg << 2);
        const int z = z0 + zg * 64 + m * 32 + zr;
        atomicAdd(out + (size_t)z * KOUT + kq + n * 32, acc[m][n][r]);
      }
}

extern "C" void kernel_launch(void* const* d_in, const int* in_sizes, int n_in,
                              void* d_out, int out_size, void* d_ws, size_t ws_size,
                              hipStream_t stream) {
  const float* features = (const float*)d_in[0];  // [16384, 127]
  const float* W        = (const float*)d_in[1];  // [128, 2080]
  const float* T        = (const float*)d_in[2];  // [2080, 16384]
  float* out = (float*)d_out;                     // [16384, 128] f32
  _Float16* K3h = (_Float16*)d_ws;                // [128, 16384] f16 (4 MB)
  _Float16* Wf  = (_Float16*)d_out;               // 520*512*2 = 520 KB scratch, pre-memset

  k_wf<<<dim3(130), dim3(256), 0, stream>>>(W, Wf);
  k_wt<<<dim3(1024), dim3(256), 0, stream>>>(T, Wf, K3h);
  hipMemsetAsync(d_out, 0, (size_t)ZTOT * KOUT * sizeof(float), stream);
  k_qf<<<dim3(512), dim3(256), 0, stream>>>(features, K3h, out);
}